// Round 15
// baseline (255.134 us; speedup 1.0000x reference)
//
#include <hip/hip_runtime.h>
#include <math.h>

// ---------------------------------------------------------------------------
// GCN: h1 = relu(Agg(x@W1)+b1); h2 = relu(Agg(h1@W2)+b2); out = sigmoid(h2@Wfc+bfc)
// Agg(xl)[dst] = dinv[dst] * ( sum_{src->dst} xl_s[src] + xl_s[dst] )
//   where xl_s[n] = (x@W)[n] * dinv[n]   (source-side norm folded into GEMM)
// R2-R9: scan / dinv-fold / counting-sort CSR (no global atomics).
// R10: MFMA GEMMs. R11-R13: fold-free 8-node/wave agg + unrolled gather chains.
// R14: gemm2 fused into layer-1 agg (LDS A-tile + 8 MFMA per wave).
// R15a: conflict-free LDS weight staging (consecutive lanes -> consecutive
//       columns; was 8-way conflicted at stride 144B: 1.7M SQ_LDS_BANK_CONFLICT).
// R15b: bucket width 512 -> 256 (NBUK 391): k_bucket 0.77 -> 1.5 blocks/CU.
// ---------------------------------------------------------------------------

typedef __attribute__((ext_vector_type(8))) short bf16x8;
typedef __attribute__((ext_vector_type(4))) float f32x4;
typedef __attribute__((ext_vector_type(2))) float f32x2;

#define CHUNKS 1024
#define BW 256          // bucket width (nodes)

__device__ __forceinline__ unsigned short f2bf(float f) {
    unsigned u = __float_as_uint(f);
    u += 0x7FFFu + ((u >> 16) & 1u);   // round-to-nearest-even
    return (unsigned short)(u >> 16);
}
__device__ __forceinline__ unsigned packbf(float a, float b) {
    return (unsigned)f2bf(a) | ((unsigned)f2bf(b) << 16);
}
// accumulate 8 bf16 (one uint4) into 4 packed f32x2 accumulators
__device__ __forceinline__ void upadd2(uint4 g, f32x2* a) {
    a[0] += (f32x2){__uint_as_float(g.x << 16), __uint_as_float(g.x & 0xFFFF0000u)};
    a[1] += (f32x2){__uint_as_float(g.y << 16), __uint_as_float(g.y & 0xFFFF0000u)};
    a[2] += (f32x2){__uint_as_float(g.z << 16), __uint_as_float(g.z & 0xFFFF0000u)};
    a[3] += (f32x2){__uint_as_float(g.w << 16), __uint_as_float(g.w & 0xFFFF0000u)};
}

// ---- CSR build: bucketed counting sort (no global atomics) ----------------
// Bucket = dst >> 8 (width 256, NBUK = 391). 1024 edge chunks.
__global__ __launch_bounds__(256) void k_hist(const int* __restrict__ col, int E,
                                              int NBUK, int CH,
                                              int* __restrict__ hist_g) {
    __shared__ int h[512];
    for (int i = threadIdx.x; i < NBUK; i += 256) h[i] = 0;
    __syncthreads();
    int base = blockIdx.x * CH, hi = min(base + CH, E);
    for (int e = base + (int)threadIdx.x; e < hi; e += 256)
        atomicAdd(&h[col[e] >> 8], 1);
    __syncthreads();
    for (int i = threadIdx.x; i < NBUK; i += 256)
        hist_g[blockIdx.x * NBUK + i] = h[i];
}

// One block per bucket: exclusive scan of hist over 1024 chunks (4/thread).
__global__ __launch_bounds__(256) void k_colscan(const int* __restrict__ hist_g, int NBUK,
                                                 int* __restrict__ histOff,
                                                 int* __restrict__ bucketTotal) {
    __shared__ int s[256];
    const int b = blockIdx.x, t = threadIdx.x;
    int v[4], sum = 0;
#pragma unroll
    for (int j = 0; j < 4; ++j) {
        v[j] = hist_g[(t * 4 + j) * NBUK + b];
        sum += v[j];
    }
    s[t] = sum;
    __syncthreads();
    for (int off = 1; off < 256; off <<= 1) {
        int u = (t >= off) ? s[t - off] : 0;
        __syncthreads();
        s[t] += u;
        __syncthreads();
    }
    int run = s[t] - sum;
#pragma unroll
    for (int j = 0; j < 4; ++j) {
        histOff[b * CHUNKS + t * 4 + j] = run;
        run += v[j];
    }
    if (t == 255) bucketTotal[b] = run;
}

// Single 512-thread block: exclusive scan of bucket totals (NBUK <= 512).
__global__ __launch_bounds__(512) void k_scan_tot(const int* __restrict__ bucketTotal,
                                                  int NBUK, int E, int N,
                                                  int* __restrict__ bucketBase,
                                                  int* __restrict__ row_off) {
    __shared__ int s[512];
    int t = threadIdx.x;
    int v = (t < NBUK) ? bucketTotal[t] : 0;
    s[t] = v;
    __syncthreads();
    for (int off = 1; off < 512; off <<= 1) {
        int u = (t >= off) ? s[t - off] : 0;
        __syncthreads();
        s[t] += u;
        __syncthreads();
    }
    if (t < NBUK) bucketBase[t] = s[t] - v;
    if (t == 0) row_off[N] = E;
}

__global__ __launch_bounds__(256) void k_scatter(const int* __restrict__ row,
                                                 const int* __restrict__ col, int E,
                                                 int NBUK, int CH,
                                                 const int* __restrict__ bucketBase,
                                                 const int* __restrict__ histOff,
                                                 unsigned* __restrict__ ebuf) {
    __shared__ int cur[512];
    for (int i = threadIdx.x; i < NBUK; i += 256)
        cur[i] = bucketBase[i] + histOff[i * CHUNKS + blockIdx.x];
    __syncthreads();
    int base = blockIdx.x * CH, hi = min(base + CH, E);
    for (int e = base + (int)threadIdx.x; e < hi; e += 256) {
        int d = col[e], src = row[e];
        int b = d >> 8;
        int pos = atomicAdd(&cur[b], 1);             // LDS atomic
        ebuf[pos] = ((unsigned)(d & (BW - 1)) << 17) | (unsigned)src;
    }
}

// One block (256 thr) per bucket of 256 nodes: local hist -> scan ->
// row_off/dinv -> LDS-cursor scatter of src into csr_src.
__global__ __launch_bounds__(256) void k_bucket(const unsigned* __restrict__ ebuf,
                                                const int* __restrict__ bucketBase,
                                                const int* __restrict__ bucketTotal,
                                                int N,
                                                int* __restrict__ row_off,
                                                float* __restrict__ dinv,
                                                int* __restrict__ csr_src) {
    __shared__ int hc[256], of[256];
    const int bid = blockIdx.x, t = threadIdx.x;
    const int base = bucketBase[bid];
    const int cnt  = bucketTotal[bid];
    hc[t] = 0;
    __syncthreads();
    for (int i = t; i < cnt; i += 256)
        atomicAdd(&hc[ebuf[base + i] >> 17], 1);
    __syncthreads();
    int v = hc[t];
    of[t] = v;
    __syncthreads();
    for (int off = 1; off < 256; off <<= 1) {
        int u = (t >= off) ? of[t - off] : 0;
        __syncthreads();
        of[t] += u;
        __syncthreads();
    }
    int excl = of[t] - v;
    int node = bid * BW + t;
    if (node < N) {
        row_off[node] = base + excl;
        dinv[node] = rsqrtf((float)(v + 1));   // +1 self loop
    }
    of[t] = excl;
    __syncthreads();
    for (int i = t; i < cnt; i += 256) {
        unsigned e = ebuf[base + i];
        int dl = (int)(e >> 17), src = (int)(e & 0x1FFFFu);
        int pos = atomicAdd(&of[dl], 1);       // LDS atomic
        csr_src[base + pos] = src;
    }
}

// ---- MFMA GEMM (layer 1) --------------------------------------------------
template <int K, bool BF16IN>
__global__ __launch_bounds__(256) void k_gemm_mfma(const void* __restrict__ xin,
                                                   const float* __restrict__ W,
                                                   const float* __restrict__ dinv,
                                                   unsigned short* __restrict__ out,
                                                   int N) {
    constexpr int KS = K + 8;
    __shared__ short sX[64 * KS];
    __shared__ short sW[64 * KS];
    const int tid = threadIdx.x;
    const int wv = tid >> 6, lane = tid & 63;
    const int q = lane >> 4, m = lane & 15;
    const int nb = blockIdx.x * 64;

    // stage W^T: consecutive lanes -> consecutive k (linear LDS, no conflicts);
    // global read strided but W is an L2-hot <=32KB table.
    for (int i = tid; i < K * 64; i += 256) {
        int c = i / K, k = i % K;
        sW[c * KS + k] = (short)f2bf(W[k * 64 + c]);
    }
    if (BF16IN) {
        const unsigned short* xb = (const unsigned short*)xin;
        for (int i = tid; i < 64 * (K / 8); i += 256) {
            int r = i / (K / 8), c8 = (i % (K / 8)) * 8;
            int node = nb + r;
            uint4 v = make_uint4(0u, 0u, 0u, 0u);
            if (node < N) v = *(const uint4*)(xb + (size_t)node * K + c8);
            *(uint4*)(&sX[r * KS + c8]) = v;
        }
    } else {
        const float* xf = (const float*)xin;
        for (int i = tid; i < 64 * (K / 8); i += 256) {
            int r = i / (K / 8), c8 = (i % (K / 8)) * 8;
            int node = nb + r;
            uint4 v = make_uint4(0u, 0u, 0u, 0u);
            if (node < N) {
                float4 lo = *(const float4*)(xf + (size_t)node * K + c8);
                float4 hi = *(const float4*)(xf + (size_t)node * K + c8 + 4);
                v.x = packbf(lo.x, lo.y);
                v.y = packbf(lo.z, lo.w);
                v.z = packbf(hi.x, hi.y);
                v.w = packbf(hi.z, hi.w);
            }
            *(uint4*)(&sX[r * KS + c8]) = v;
        }
    }
    __syncthreads();

    f32x4 acc[4] = {};
    const short* aRow = &sX[(wv * 16 + m) * KS + q * 8];
#pragma unroll
    for (int k0 = 0; k0 < K; k0 += 32) {
        bf16x8 a = *(const bf16x8*)(aRow + k0);
#pragma unroll
        for (int ft = 0; ft < 4; ++ft) {
            bf16x8 b = *(const bf16x8*)(&sW[(ft * 16 + m) * KS + k0 + q * 8]);
            acc[ft] = __builtin_amdgcn_mfma_f32_16x16x32_bf16(a, b, acc[ft], 0, 0, 0);
        }
    }
#pragma unroll
    for (int r = 0; r < 4; ++r) {
        int node = nb + wv * 16 + q * 4 + r;
        if (node < N) {
            float di = dinv[node];
#pragma unroll
            for (int ft = 0; ft < 4; ++ft)
                out[(size_t)node * 64 + ft * 16 + m] = f2bf(acc[ft][r] * di);
        }
    }
}

// ---- fused layer-1 agg + gemm2 --------------------------------------------
__global__ __launch_bounds__(256) void k_agg_g2(const unsigned short* __restrict__ xl,
                                                const int* __restrict__ row_off,
                                                const int* __restrict__ csr_src,
                                                const float* __restrict__ dinv,
                                                const float* __restrict__ bias,
                                                const float* __restrict__ W2,
                                                unsigned short* __restrict__ out, int N) {
    constexpr int KS = 72;               // 64 + 8 pad (bf16 elems)
    __shared__ short sH[4 * 16 * KS];    // per-wave 16x64 A-tiles
    __shared__ short sW2[64 * KS];       // W2^T bf16
    const int tid = threadIdx.x;
    const int wv = tid >> 6, lane = tid & 63;
    const int s = lane >> 3, o = lane & 7;
    const int q = lane >> 4, m = lane & 15;

    // stage W2^T: consecutive lanes -> consecutive k (linear LDS writes).
    for (int i = tid; i < 64 * 64; i += 256) {
        int n = i >> 6, k = i & 63;
        sW2[n * KS + k] = (short)f2bf(W2[k * 64 + n]);
    }
    short* myH = &sH[wv * 16 * KS];
    for (int i = lane; i < 8 * KS / 4; i += 64)
        ((unsigned long long*)(myH + 8 * KS))[i] = 0ull;
    __syncthreads();

    const int base8 = (blockIdx.x * 4 + wv) * 8;
    int node = base8 + s;
    const bool active = node < N;
    node = min(node, N - 1);
    const int beg = row_off[node];
    const int deg = row_off[node + 1] - beg;
    const int cnt = active ? deg + 1 : 0;
    int mx = cnt;
    mx = max(mx, __shfl_xor(mx, 8, 64));
    mx = max(mx, __shfl_xor(mx, 16, 64));
    mx = max(mx, __shfl_xor(mx, 32, 64));
    const char* xlb = (const char*)xl;
    const unsigned loff = (unsigned)(o << 4);
    f32x2 acc0[4] = {}, acc1[4] = {};
    int idx[4];
#pragma unroll
    for (int j = 0; j < 4; ++j) idx[j] = (j < deg) ? csr_src[beg + j] : node;
    for (int it = 0; it < mx; it += 4) {
        int c[4];
        bool v[4];
#pragma unroll
        for (int j = 0; j < 4; ++j) {
            c[j] = idx[j];
            v[j] = (it + j) < cnt;
            idx[j] = (it + 4 + j < deg) ? csr_src[beg + it + 4 + j] : node;
        }
        uint4 g0 = *(const uint4*)(xlb + (((unsigned)c[0] << 7) | loff));
        uint4 g1 = *(const uint4*)(xlb + (((unsigned)c[1] << 7) | loff));
        uint4 g2 = *(const uint4*)(xlb + (((unsigned)c[2] << 7) | loff));
        uint4 g3 = *(const uint4*)(xlb + (((unsigned)c[3] << 7) | loff));
        if (!v[0]) g0 = make_uint4(0u, 0u, 0u, 0u);
        if (!v[1]) g1 = make_uint4(0u, 0u, 0u, 0u);
        if (!v[2]) g2 = make_uint4(0u, 0u, 0u, 0u);
        if (!v[3]) g3 = make_uint4(0u, 0u, 0u, 0u);
        upadd2(g0, acc0);
        upadd2(g1, acc1);
        upadd2(g2, acc0);
        upadd2(g3, acc1);
    }
#pragma unroll
    for (int j = 0; j < 4; ++j) acc0[j] += acc1[j];
    {
        float di = dinv[node];
        float4 blo = *(const float4*)(bias + o * 8);
        float4 bhi = *(const float4*)(bias + o * 8 + 4);
        uint4 h;
        h.x = packbf(fmaxf(acc0[0].x * di + blo.x, 0.f), fmaxf(acc0[0].y * di + blo.y, 0.f));
        h.y = packbf(fmaxf(acc0[1].x * di + blo.z, 0.f), fmaxf(acc0[1].y * di + blo.w, 0.f));
        h.z = packbf(fmaxf(acc0[2].x * di + bhi.x, 0.f), fmaxf(acc0[2].y * di + bhi.y, 0.f));
        h.w = packbf(fmaxf(acc0[3].x * di + bhi.z, 0.f), fmaxf(acc0[3].y * di + bhi.w, 0.f));
        *(uint4*)(myH + s * KS + o * 8) = h;     // same-wave LDS, no barrier
    }
    f32x4 accm[4] = {};
#pragma unroll
    for (int k0 = 0; k0 < 64; k0 += 32) {
        bf16x8 a = *(const bf16x8*)(myH + m * KS + q * 8 + k0);
#pragma unroll
        for (int ft = 0; ft < 4; ++ft) {
            bf16x8 b = *(const bf16x8*)(&sW2[(ft * 16 + m) * KS + k0 + q * 8]);
            accm[ft] = __builtin_amdgcn_mfma_f32_16x16x32_bf16(a, b, accm[ft], 0, 0, 0);
        }
    }
    if (q < 2) {                          // valid rows 0..7
#pragma unroll
        for (int r = 0; r < 4; ++r) {
            int node2 = base8 + q * 4 + r;
            if (node2 < N) {
                float di2 = dinv[node2];
#pragma unroll
                for (int ft = 0; ft < 4; ++ft)
                    out[(size_t)node2 * 64 + ft * 16 + m] = f2bf(accm[ft][r] * di2);
            }
        }
    }
}

// Layer-2 agg + final FC + sigmoid (4-way chains; octet fold shfl 1/2/4).
__global__ __launch_bounds__(256) void k_agg_fc(const unsigned short* __restrict__ xl,
                                                const int* __restrict__ row_off,
                                                const int* __restrict__ csr_src,
                                                const float* __restrict__ dinv,
                                                const float* __restrict__ bias,
                                                const float* __restrict__ Wfc,
                                                const float* __restrict__ bfc,
                                                float* __restrict__ out, int N) {
    const int wave = threadIdx.x >> 6, lane = threadIdx.x & 63;
    const int s = lane >> 3, o = lane & 7;
    int node = (blockIdx.x * 4 + wave) * 8 + s;
    const bool active = node < N;
    node = min(node, N - 1);
    const int beg = row_off[node];
    const int deg = row_off[node + 1] - beg;
    const int cnt = active ? deg + 1 : 0;
    int mx = cnt;
    mx = max(mx, __shfl_xor(mx, 8, 64));
    mx = max(mx, __shfl_xor(mx, 16, 64));
    mx = max(mx, __shfl_xor(mx, 32, 64));
    const char* xlb = (const char*)xl;
    const unsigned loff = (unsigned)(o << 4);
    f32x2 acc0[4] = {}, acc1[4] = {};
    int idx[4];
#pragma unroll
    for (int j = 0; j < 4; ++j) idx[j] = (j < deg) ? csr_src[beg + j] : node;
    for (int it = 0; it < mx; it += 4) {
        int c[4];
        bool v[4];
#pragma unroll
        for (int j = 0; j < 4; ++j) {
            c[j] = idx[j];
            v[j] = (it + j) < cnt;
            idx[j] = (it + 4 + j < deg) ? csr_src[beg + it + 4 + j] : node;
        }
        uint4 g0 = *(const uint4*)(xlb + (((unsigned)c[0] << 7) | loff));
        uint4 g1 = *(const uint4*)(xlb + (((unsigned)c[1] << 7) | loff));
        uint4 g2 = *(const uint4*)(xlb + (((unsigned)c[2] << 7) | loff));
        uint4 g3 = *(const uint4*)(xlb + (((unsigned)c[3] << 7) | loff));
        if (!v[0]) g0 = make_uint4(0u, 0u, 0u, 0u);
        if (!v[1]) g1 = make_uint4(0u, 0u, 0u, 0u);
        if (!v[2]) g2 = make_uint4(0u, 0u, 0u, 0u);
        if (!v[3]) g3 = make_uint4(0u, 0u, 0u, 0u);
        upadd2(g0, acc0);
        upadd2(g1, acc1);
        upadd2(g2, acc0);
        upadd2(g3, acc1);
    }
#pragma unroll
    for (int j = 0; j < 4; ++j) acc0[j] += acc1[j];
    const float di = dinv[node];
    float4 blo = *(const float4*)(bias + o * 8);
    float4 bhi = *(const float4*)(bias + o * 8 + 4);
    float4 wlo = *(const float4*)(Wfc + o * 8);
    float4 whi = *(const float4*)(Wfc + o * 8 + 4);
    float v = 0.f;
    v += fmaxf(acc0[0].x * di + blo.x, 0.f) * wlo.x;
    v += fmaxf(acc0[0].y * di + blo.y, 0.f) * wlo.y;
    v += fmaxf(acc0[1].x * di + blo.z, 0.f) * wlo.z;
    v += fmaxf(acc0[1].y * di + blo.w, 0.f) * wlo.w;
    v += fmaxf(acc0[2].x * di + bhi.x, 0.f) * whi.x;
    v += fmaxf(acc0[2].y * di + bhi.y, 0.f) * whi.y;
    v += fmaxf(acc0[3].x * di + bhi.z, 0.f) * whi.z;
    v += fmaxf(acc0[3].y * di + bhi.w, 0.f) * whi.w;
    v += __shfl_xor(v, 1, 64);
    v += __shfl_xor(v, 2, 64);
    v += __shfl_xor(v, 4, 64);
    if (active && o == 0) out[node] = 1.f / (1.f + expf(-(v + bfc[0])));
}

extern "C" void kernel_launch(void* const* d_in, const int* in_sizes, int n_in,
                              void* d_out, int out_size, void* d_ws, size_t ws_size,
                              hipStream_t stream) {
    const float* x   = (const float*)d_in[0];
    const int*   ei  = (const int*)d_in[1];   // [2, E]: row then col
    const float* W1  = (const float*)d_in[2];
    const float* b1  = (const float*)d_in[3];
    const float* W2  = (const float*)d_in[4];
    const float* b2  = (const float*)d_in[5];
    const float* Wfc = (const float*)d_in[6];
    const float* bfc = (const float*)d_in[7];
    float* out = (float*)d_out;

    const int H = in_sizes[3];          // 64
    const int D = in_sizes[2] / H;      // 128
    const int N = in_sizes[0] / D;      // 100000
    const int E = in_sizes[1] / 2;      // 1600000
    const int* row = ei;
    const int* col = ei + E;
    const int NBUK = (N + BW - 1) / BW; // 391 buckets of 256 nodes
    const int CH   = (E + CHUNKS - 1) / CHUNKS;

    // Workspace carve-up (256B aligned slices)
    char* p = (char*)d_ws;
    auto carve = [&](size_t bytes) {
        char* r = p;
        p += (bytes + 255) & ~(size_t)255;
        return (void*)r;
    };
    int*            hist_g      = (int*)carve((size_t)CHUNKS * 512 * 4);
    int*            histOff     = (int*)carve((size_t)512 * CHUNKS * 4);
    int*            bucketTotal = (int*)carve((size_t)512 * 4);
    int*            bucketBase  = (int*)carve((size_t)512 * 4);
    unsigned*       ebuf        = (unsigned*)carve((size_t)E * 4);
    int*            csr_src     = (int*)carve((size_t)E * 4);
    int*            row_off     = (int*)carve((size_t)(N + 1) * 4);
    float*          dinv        = (float*)carve((size_t)N * 4);
    unsigned short* bufXL       = (unsigned short*)carve((size_t)N * 64 * 2);
    unsigned short* bufXL2      = (unsigned short*)carve((size_t)N * 64 * 2);
    (void)ws_size;

    const int TB = 256;
    // 1. CSR build (bucketed counting sort; no global atomics)
    k_hist<<<CHUNKS, TB, 0, stream>>>(col, E, NBUK, CH, hist_g);
    k_colscan<<<NBUK, TB, 0, stream>>>(hist_g, NBUK, histOff, bucketTotal);
    k_scan_tot<<<1, 512, 0, stream>>>(bucketTotal, NBUK, E, N, bucketBase, row_off);
    k_scatter<<<CHUNKS, TB, 0, stream>>>(row, col, E, NBUK, CH, bucketBase, histOff, ebuf);
    k_bucket<<<NBUK, TB, 0, stream>>>(ebuf, bucketBase, bucketTotal, N,
                                      row_off, dinv, csr_src);

    int gemmGrid = (N + 63) / 64;       // 1563
    int aggGrid  = (N + 31) / 32;       // 3125 (8 nodes/wave x 4 waves)
    // 2. layer 1 GEMM: xl = bf16((x@W1)*dinv)
    k_gemm_mfma<128, false><<<gemmGrid, TB, 0, stream>>>(x, W1, dinv, bufXL, N);
    // 3. fused layer-1 agg + gemm2: xl2 = bf16(dinv*(relu(dinv*Agg(xl)+b1)@W2))
    k_agg_g2<<<aggGrid, TB, 0, stream>>>(bufXL, row_off, csr_src, dinv, b1, W2, bufXL2, N);
    // 4. layer-2 agg + FC + sigmoid
    k_agg_fc<<<aggGrid, TB, 0, stream>>>(bufXL2, row_off, csr_src, dinv, b2, Wfc, bfc, out, N);
}

// Round 16
// 219.969 us; speedup vs baseline: 1.1599x; 1.1599x over previous
//
#include <hip/hip_runtime.h>
#include <math.h>

// ---------------------------------------------------------------------------
// GCN: h1 = relu(Agg(x@W1)+b1); h2 = relu(Agg(h1@W2)+b2); out = sigmoid(h2@Wfc+bfc)
// Agg(xl)[dst] = dinv[dst] * ( sum_{src->dst} xl_s[src] + xl_s[dst] )
//   where xl_s[n] = (x@W)[n] * dinv[n]   (source-side norm folded into GEMM)
// R2-R9: scan / dinv-fold / counting-sort CSR. R10: MFMA GEMMs.
// R11-R13: fold-free 8-node/wave agg + unrolled gather chains.
// R14: gemm2 fused into layer-1 agg. (217us)
// R15: FAILED (-38us): "conflict-free" staging broke global coalescing
//      (stride-256B weight reads x 3125 blocks beat the 3us LDS stall).
// R16: revert to R14 + k_prep: one-time bf16 W^T tables in workspace ->
//      staging is coalesced global AND linear LDS (both conflict-free).
// ---------------------------------------------------------------------------

typedef __attribute__((ext_vector_type(8))) short bf16x8;
typedef __attribute__((ext_vector_type(4))) float f32x4;
typedef __attribute__((ext_vector_type(2))) float f32x2;

#define CHUNKS 1024

__device__ __forceinline__ unsigned short f2bf(float f) {
    unsigned u = __float_as_uint(f);
    u += 0x7FFFu + ((u >> 16) & 1u);   // round-to-nearest-even
    return (unsigned short)(u >> 16);
}
__device__ __forceinline__ unsigned packbf(float a, float b) {
    return (unsigned)f2bf(a) | ((unsigned)f2bf(b) << 16);
}
// accumulate 8 bf16 (one uint4) into 4 packed f32x2 accumulators
__device__ __forceinline__ void upadd2(uint4 g, f32x2* a) {
    a[0] += (f32x2){__uint_as_float(g.x << 16), __uint_as_float(g.x & 0xFFFF0000u)};
    a[1] += (f32x2){__uint_as_float(g.y << 16), __uint_as_float(g.y & 0xFFFF0000u)};
    a[2] += (f32x2){__uint_as_float(g.z << 16), __uint_as_float(g.z & 0xFFFF0000u)};
    a[3] += (f32x2){__uint_as_float(g.w << 16), __uint_as_float(g.w & 0xFFFF0000u)};
}

// One-time weight transpose to bf16: wt[n*K + k] = bf16(W[k*64 + n]).
// Uncoalesced reads but runs ONCE (2 blocks), not per compute block.
__global__ __launch_bounds__(256) void k_prep(const float* __restrict__ W1,
                                              const float* __restrict__ W2,
                                              unsigned short* __restrict__ w1t,
                                              unsigned short* __restrict__ w2t) {
    if (blockIdx.x == 0) {
        for (int i = threadIdx.x; i < 64 * 128; i += 256) {
            int n = i >> 7, k = i & 127;
            w1t[i] = f2bf(W1[k * 64 + n]);
        }
    } else {
        for (int i = threadIdx.x; i < 64 * 64; i += 256) {
            int n = i >> 6, k = i & 63;
            w2t[i] = f2bf(W2[k * 64 + n]);
        }
    }
}

// ---- CSR build: bucketed counting sort (no global atomics) ----------------
// Bucket = dst >> 9 (width 512, NBUK=196). 1024 edge chunks.
__global__ __launch_bounds__(256) void k_hist(const int* __restrict__ col, int E,
                                              int NBUK, int CH,
                                              int* __restrict__ hist_g) {
    __shared__ int h[256];
    for (int i = threadIdx.x; i < NBUK; i += 256) h[i] = 0;
    __syncthreads();
    int base = blockIdx.x * CH, hi = min(base + CH, E);
    for (int e = base + (int)threadIdx.x; e < hi; e += 256)
        atomicAdd(&h[col[e] >> 9], 1);
    __syncthreads();
    for (int i = threadIdx.x; i < NBUK; i += 256)
        hist_g[blockIdx.x * NBUK + i] = h[i];
}

__global__ __launch_bounds__(256) void k_colscan(const int* __restrict__ hist_g, int NBUK,
                                                 int* __restrict__ histOff,
                                                 int* __restrict__ bucketTotal) {
    __shared__ int s[256];
    const int b = blockIdx.x, t = threadIdx.x;
    int v[4], sum = 0;
#pragma unroll
    for (int j = 0; j < 4; ++j) {
        v[j] = hist_g[(t * 4 + j) * NBUK + b];
        sum += v[j];
    }
    s[t] = sum;
    __syncthreads();
    for (int off = 1; off < 256; off <<= 1) {
        int u = (t >= off) ? s[t - off] : 0;
        __syncthreads();
        s[t] += u;
        __syncthreads();
    }
    int run = s[t] - sum;
#pragma unroll
    for (int j = 0; j < 4; ++j) {
        histOff[b * CHUNKS + t * 4 + j] = run;
        run += v[j];
    }
    if (t == 255) bucketTotal[b] = run;
}

__global__ __launch_bounds__(256) void k_scan_tot(const int* __restrict__ bucketTotal,
                                                  int NBUK, int E, int N,
                                                  int* __restrict__ bucketBase,
                                                  int* __restrict__ row_off) {
    __shared__ int s[256];
    int t = threadIdx.x;
    int v = (t < NBUK) ? bucketTotal[t] : 0;
    s[t] = v;
    __syncthreads();
    for (int off = 1; off < 256; off <<= 1) {
        int u = (t >= off) ? s[t - off] : 0;
        __syncthreads();
        s[t] += u;
        __syncthreads();
    }
    if (t < NBUK) bucketBase[t] = s[t] - v;
    if (t == 0) row_off[N] = E;
}

__global__ __launch_bounds__(256) void k_scatter(const int* __restrict__ row,
                                                 const int* __restrict__ col, int E,
                                                 int NBUK, int CH,
                                                 const int* __restrict__ bucketBase,
                                                 const int* __restrict__ histOff,
                                                 unsigned* __restrict__ ebuf) {
    __shared__ int cur[256];
    for (int i = threadIdx.x; i < NBUK; i += 256)
        cur[i] = bucketBase[i] + histOff[i * CHUNKS + blockIdx.x];
    __syncthreads();
    int base = blockIdx.x * CH, hi = min(base + CH, E);
    for (int e = base + (int)threadIdx.x; e < hi; e += 256) {
        int d = col[e], src = row[e];
        int b = d >> 9;
        int pos = atomicAdd(&cur[b], 1);             // LDS atomic
        ebuf[pos] = ((unsigned)(d & 511) << 17) | (unsigned)src;
    }
}

__global__ __launch_bounds__(512) void k_bucket(const unsigned* __restrict__ ebuf,
                                                const int* __restrict__ bucketBase,
                                                const int* __restrict__ bucketTotal,
                                                int N,
                                                int* __restrict__ row_off,
                                                float* __restrict__ dinv,
                                                int* __restrict__ csr_src) {
    __shared__ int hc[512], of[512];
    const int bid = blockIdx.x, t = threadIdx.x;
    const int base = bucketBase[bid];
    const int cnt  = bucketTotal[bid];
    hc[t] = 0;
    __syncthreads();
    for (int i = t; i < cnt; i += 512)
        atomicAdd(&hc[ebuf[base + i] >> 17], 1);
    __syncthreads();
    int v = hc[t];
    of[t] = v;
    __syncthreads();
    for (int off = 1; off < 512; off <<= 1) {
        int u = (t >= off) ? of[t - off] : 0;
        __syncthreads();
        of[t] += u;
        __syncthreads();
    }
    int excl = of[t] - v;
    int node = bid * 512 + t;
    if (node < N) {
        row_off[node] = base + excl;
        dinv[node] = rsqrtf((float)(v + 1));   // +1 self loop
    }
    of[t] = excl;
    __syncthreads();
    for (int i = t; i < cnt; i += 512) {
        unsigned e = ebuf[base + i];
        int dl = (int)(e >> 17), src = (int)(e & 0x1FFFFu);
        int pos = atomicAdd(&of[dl], 1);       // LDS atomic
        csr_src[base + pos] = src;
    }
}

// ---- MFMA GEMM (layer 1) --------------------------------------------------
// Weights come pre-transposed bf16 (wt[n*K+k]) -> staging is coalesced
// uint4 global reads + linear LDS writes (conflict-free both sides).
template <int K>
__global__ __launch_bounds__(256) void k_gemm_mfma(const float* __restrict__ xf,
                                                   const unsigned short* __restrict__ wt,
                                                   const float* __restrict__ dinv,
                                                   unsigned short* __restrict__ out,
                                                   int N) {
    constexpr int KS = K + 8;
    __shared__ short sX[64 * KS];
    __shared__ short sW[64 * KS];
    const int tid = threadIdx.x;
    const int wv = tid >> 6, lane = tid & 63;
    const int q = lane >> 4, m = lane & 15;
    const int nb = blockIdx.x * 64;

    // stage W^T (bf16, pre-transposed): 8 elems/thread, linear both sides
    for (int i = tid; i < 64 * (K / 8); i += 256) {
        int r = i / (K / 8), kb = i % (K / 8);
        *(uint4*)(&sW[r * KS + kb * 8]) = ((const uint4*)wt)[i];
    }
    // stage X rows as bf16
    for (int i = tid; i < 64 * (K / 8); i += 256) {
        int r = i / (K / 8), c8 = (i % (K / 8)) * 8;
        int node = nb + r;
        uint4 v = make_uint4(0u, 0u, 0u, 0u);
        if (node < N) {
            float4 lo = *(const float4*)(xf + (size_t)node * K + c8);
            float4 hi = *(const float4*)(xf + (size_t)node * K + c8 + 4);
            v.x = packbf(lo.x, lo.y);
            v.y = packbf(lo.z, lo.w);
            v.z = packbf(hi.x, hi.y);
            v.w = packbf(hi.z, hi.w);
        }
        *(uint4*)(&sX[r * KS + c8]) = v;
    }
    __syncthreads();

    f32x4 acc[4] = {};
    const short* aRow = &sX[(wv * 16 + m) * KS + q * 8];
#pragma unroll
    for (int k0 = 0; k0 < K; k0 += 32) {
        bf16x8 a = *(const bf16x8*)(aRow + k0);
#pragma unroll
        for (int ft = 0; ft < 4; ++ft) {
            bf16x8 b = *(const bf16x8*)(&sW[(ft * 16 + m) * KS + k0 + q * 8]);
            acc[ft] = __builtin_amdgcn_mfma_f32_16x16x32_bf16(a, b, acc[ft], 0, 0, 0);
        }
    }
#pragma unroll
    for (int r = 0; r < 4; ++r) {
        int node = nb + wv * 16 + q * 4 + r;
        if (node < N) {
            float di = dinv[node];
#pragma unroll
            for (int ft = 0; ft < 4; ++ft)
                out[(size_t)node * 64 + ft * 16 + m] = f2bf(acc[ft][r] * di);
        }
    }
}

// ---- fused layer-1 agg + gemm2 --------------------------------------------
__global__ __launch_bounds__(256) void k_agg_g2(const unsigned short* __restrict__ xl,
                                                const int* __restrict__ row_off,
                                                const int* __restrict__ csr_src,
                                                const float* __restrict__ dinv,
                                                const float* __restrict__ bias,
                                                const unsigned short* __restrict__ w2t,
                                                unsigned short* __restrict__ out, int N) {
    constexpr int KS = 72;               // 64 + 8 pad (bf16 elems)
    __shared__ short sH[4 * 16 * KS];    // per-wave 16x64 A-tiles
    __shared__ short sW2[64 * KS];       // W2^T bf16
    const int tid = threadIdx.x;
    const int wv = tid >> 6, lane = tid & 63;
    const int s = lane >> 3, o = lane & 7;
    const int q = lane >> 4, m = lane & 15;

    // stage W2^T (pre-transposed): coalesced global, linear LDS
    for (int i = tid; i < 64 * 8; i += 256) {
        int r = i >> 3, kb = i & 7;
        *(uint4*)(&sW2[r * KS + kb * 8]) = ((const uint4*)w2t)[i];
    }
    short* myH = &sH[wv * 16 * KS];
    for (int i = lane; i < 8 * KS / 4; i += 64)
        ((unsigned long long*)(myH + 8 * KS))[i] = 0ull;
    __syncthreads();

    const int base8 = (blockIdx.x * 4 + wv) * 8;
    int node = base8 + s;
    const bool active = node < N;
    node = min(node, N - 1);
    const int beg = row_off[node];
    const int deg = row_off[node + 1] - beg;
    const int cnt = active ? deg + 1 : 0;
    int mx = cnt;
    mx = max(mx, __shfl_xor(mx, 8, 64));
    mx = max(mx, __shfl_xor(mx, 16, 64));
    mx = max(mx, __shfl_xor(mx, 32, 64));
    const char* xlb = (const char*)xl;
    const unsigned loff = (unsigned)(o << 4);
    f32x2 acc0[4] = {}, acc1[4] = {};
    int idx[4];
#pragma unroll
    for (int j = 0; j < 4; ++j) idx[j] = (j < deg) ? csr_src[beg + j] : node;
    for (int it = 0; it < mx; it += 4) {
        int c[4];
        bool v[4];
#pragma unroll
        for (int j = 0; j < 4; ++j) {
            c[j] = idx[j];
            v[j] = (it + j) < cnt;
            idx[j] = (it + 4 + j < deg) ? csr_src[beg + it + 4 + j] : node;
        }
        uint4 g0 = *(const uint4*)(xlb + (((unsigned)c[0] << 7) | loff));
        uint4 g1 = *(const uint4*)(xlb + (((unsigned)c[1] << 7) | loff));
        uint4 g2 = *(const uint4*)(xlb + (((unsigned)c[2] << 7) | loff));
        uint4 g3 = *(const uint4*)(xlb + (((unsigned)c[3] << 7) | loff));
        if (!v[0]) g0 = make_uint4(0u, 0u, 0u, 0u);
        if (!v[1]) g1 = make_uint4(0u, 0u, 0u, 0u);
        if (!v[2]) g2 = make_uint4(0u, 0u, 0u, 0u);
        if (!v[3]) g3 = make_uint4(0u, 0u, 0u, 0u);
        upadd2(g0, acc0);
        upadd2(g1, acc1);
        upadd2(g2, acc0);
        upadd2(g3, acc1);
    }
#pragma unroll
    for (int j = 0; j < 4; ++j) acc0[j] += acc1[j];
    {
        float di = dinv[node];
        float4 blo = *(const float4*)(bias + o * 8);
        float4 bhi = *(const float4*)(bias + o * 8 + 4);
        uint4 h;
        h.x = packbf(fmaxf(acc0[0].x * di + blo.x, 0.f), fmaxf(acc0[0].y * di + blo.y, 0.f));
        h.y = packbf(fmaxf(acc0[1].x * di + blo.z, 0.f), fmaxf(acc0[1].y * di + blo.w, 0.f));
        h.z = packbf(fmaxf(acc0[2].x * di + bhi.x, 0.f), fmaxf(acc0[2].y * di + bhi.y, 0.f));
        h.w = packbf(fmaxf(acc0[3].x * di + bhi.z, 0.f), fmaxf(acc0[3].y * di + bhi.w, 0.f));
        *(uint4*)(myH + s * KS + o * 8) = h;     // same-wave LDS, no barrier
    }
    f32x4 accm[4] = {};
#pragma unroll
    for (int k0 = 0; k0 < 64; k0 += 32) {
        bf16x8 a = *(const bf16x8*)(myH + m * KS + q * 8 + k0);
#pragma unroll
        for (int ft = 0; ft < 4; ++ft) {
            bf16x8 b = *(const bf16x8*)(&sW2[(ft * 16 + m) * KS + k0 + q * 8]);
            accm[ft] = __builtin_amdgcn_mfma_f32_16x16x32_bf16(a, b, accm[ft], 0, 0, 0);
        }
    }
    if (q < 2) {                          // valid rows 0..7
#pragma unroll
        for (int r = 0; r < 4; ++r) {
            int node2 = base8 + q * 4 + r;
            if (node2 < N) {
                float di2 = dinv[node2];
#pragma unroll
                for (int ft = 0; ft < 4; ++ft)
                    out[(size_t)node2 * 64 + ft * 16 + m] = f2bf(accm[ft][r] * di2);
            }
        }
    }
}

// Layer-2 agg + final FC + sigmoid (4-way chains; octet fold shfl 1/2/4).
__global__ __launch_bounds__(256) void k_agg_fc(const unsigned short* __restrict__ xl,
                                                const int* __restrict__ row_off,
                                                const int* __restrict__ csr_src,
                                                const float* __restrict__ dinv,
                                                const float* __restrict__ bias,
                                                const float* __restrict__ Wfc,
                                                const float* __restrict__ bfc,
                                                float* __restrict__ out, int N) {
    const int wave = threadIdx.x >> 6, lane = threadIdx.x & 63;
    const int s = lane >> 3, o = lane & 7;
    int node = (blockIdx.x * 4 + wave) * 8 + s;
    const bool active = node < N;
    node = min(node, N - 1);
    const int beg = row_off[node];
    const int deg = row_off[node + 1] - beg;
    const int cnt = active ? deg + 1 : 0;
    int mx = cnt;
    mx = max(mx, __shfl_xor(mx, 8, 64));
    mx = max(mx, __shfl_xor(mx, 16, 64));
    mx = max(mx, __shfl_xor(mx, 32, 64));
    const char* xlb = (const char*)xl;
    const unsigned loff = (unsigned)(o << 4);
    f32x2 acc0[4] = {}, acc1[4] = {};
    int idx[4];
#pragma unroll
    for (int j = 0; j < 4; ++j) idx[j] = (j < deg) ? csr_src[beg + j] : node;
    for (int it = 0; it < mx; it += 4) {
        int c[4];
        bool v[4];
#pragma unroll
        for (int j = 0; j < 4; ++j) {
            c[j] = idx[j];
            v[j] = (it + j) < cnt;
            idx[j] = (it + 4 + j < deg) ? csr_src[beg + it + 4 + j] : node;
        }
        uint4 g0 = *(const uint4*)(xlb + (((unsigned)c[0] << 7) | loff));
        uint4 g1 = *(const uint4*)(xlb + (((unsigned)c[1] << 7) | loff));
        uint4 g2 = *(const uint4*)(xlb + (((unsigned)c[2] << 7) | loff));
        uint4 g3 = *(const uint4*)(xlb + (((unsigned)c[3] << 7) | loff));
        if (!v[0]) g0 = make_uint4(0u, 0u, 0u, 0u);
        if (!v[1]) g1 = make_uint4(0u, 0u, 0u, 0u);
        if (!v[2]) g2 = make_uint4(0u, 0u, 0u, 0u);
        if (!v[3]) g3 = make_uint4(0u, 0u, 0u, 0u);
        upadd2(g0, acc0);
        upadd2(g1, acc1);
        upadd2(g2, acc0);
        upadd2(g3, acc1);
    }
#pragma unroll
    for (int j = 0; j < 4; ++j) acc0[j] += acc1[j];
    const float di = dinv[node];
    float4 blo = *(const float4*)(bias + o * 8);
    float4 bhi = *(const float4*)(bias + o * 8 + 4);
    float4 wlo = *(const float4*)(Wfc + o * 8);
    float4 whi = *(const float4*)(Wfc + o * 8 + 4);
    float v = 0.f;
    v += fmaxf(acc0[0].x * di + blo.x, 0.f) * wlo.x;
    v += fmaxf(acc0[0].y * di + blo.y, 0.f) * wlo.y;
    v += fmaxf(acc0[1].x * di + blo.z, 0.f) * wlo.z;
    v += fmaxf(acc0[1].y * di + blo.w, 0.f) * wlo.w;
    v += fmaxf(acc0[2].x * di + bhi.x, 0.f) * whi.x;
    v += fmaxf(acc0[2].y * di + bhi.y, 0.f) * whi.y;
    v += fmaxf(acc0[3].x * di + bhi.z, 0.f) * whi.z;
    v += fmaxf(acc0[3].y * di + bhi.w, 0.f) * whi.w;
    v += __shfl_xor(v, 1, 64);
    v += __shfl_xor(v, 2, 64);
    v += __shfl_xor(v, 4, 64);
    if (active && o == 0) out[node] = 1.f / (1.f + expf(-(v + bfc[0])));
}

extern "C" void kernel_launch(void* const* d_in, const int* in_sizes, int n_in,
                              void* d_out, int out_size, void* d_ws, size_t ws_size,
                              hipStream_t stream) {
    const float* x   = (const float*)d_in[0];
    const int*   ei  = (const int*)d_in[1];   // [2, E]: row then col
    const float* W1  = (const float*)d_in[2];
    const float* b1  = (const float*)d_in[3];
    const float* W2  = (const float*)d_in[4];
    const float* b2  = (const float*)d_in[5];
    const float* Wfc = (const float*)d_in[6];
    const float* bfc = (const float*)d_in[7];
    float* out = (float*)d_out;

    const int H = in_sizes[3];          // 64
    const int D = in_sizes[2] / H;      // 128
    const int N = in_sizes[0] / D;      // 100000
    const int E = in_sizes[1] / 2;      // 1600000
    const int* row = ei;
    const int* col = ei + E;
    const int NBUK = (N + 511) >> 9;    // 196 buckets of 512 nodes
    const int CH   = (E + CHUNKS - 1) / CHUNKS;

    // Workspace carve-up (256B aligned slices)
    char* p = (char*)d_ws;
    auto carve = [&](size_t bytes) {
        char* r = p;
        p += (bytes + 255) & ~(size_t)255;
        return (void*)r;
    };
    int*            hist_g      = (int*)carve((size_t)CHUNKS * 256 * 4);
    int*            histOff     = (int*)carve((size_t)256 * CHUNKS * 4);
    int*            bucketTotal = (int*)carve((size_t)256 * 4);
    int*            bucketBase  = (int*)carve((size_t)256 * 4);
    unsigned*       ebuf        = (unsigned*)carve((size_t)E * 4);
    int*            csr_src     = (int*)carve((size_t)E * 4);
    int*            row_off     = (int*)carve((size_t)(N + 1) * 4);
    float*          dinv        = (float*)carve((size_t)N * 4);
    unsigned short* w1t         = (unsigned short*)carve((size_t)64 * 128 * 2);
    unsigned short* w2t         = (unsigned short*)carve((size_t)64 * 64 * 2);
    unsigned short* bufXL       = (unsigned short*)carve((size_t)N * 64 * 2);
    unsigned short* bufXL2      = (unsigned short*)carve((size_t)N * 64 * 2);
    (void)ws_size;

    const int TB = 256;
    // 0. one-time bf16 weight transposes
    k_prep<<<2, TB, 0, stream>>>(W1, W2, w1t, w2t);
    // 1. CSR build (bucketed counting sort; no global atomics)
    k_hist<<<CHUNKS, TB, 0, stream>>>(col, E, NBUK, CH, hist_g);
    k_colscan<<<NBUK, TB, 0, stream>>>(hist_g, NBUK, histOff, bucketTotal);
    k_scan_tot<<<1, TB, 0, stream>>>(bucketTotal, NBUK, E, N, bucketBase, row_off);
    k_scatter<<<CHUNKS, TB, 0, stream>>>(row, col, E, NBUK, CH, bucketBase, histOff, ebuf);
    k_bucket<<<NBUK, 512, 0, stream>>>(ebuf, bucketBase, bucketTotal, N,
                                       row_off, dinv, csr_src);

    int gemmGrid = (N + 63) / 64;       // 1563
    int aggGrid  = (N + 31) / 32;       // 3125 (8 nodes/wave x 4 waves)
    // 2. layer 1 GEMM: xl = bf16((x@W1)*dinv)
    k_gemm_mfma<128><<<gemmGrid, TB, 0, stream>>>(x, w1t, dinv, bufXL, N);
    // 3. fused layer-1 agg + gemm2: xl2 = bf16(dinv*(relu(dinv*Agg(xl)+b1)@W2))
    k_agg_g2<<<aggGrid, TB, 0, stream>>>(bufXL, row_off, csr_src, dinv, b1, w2t, bufXL2, N);
    // 4. layer-2 agg + FC + sigmoid
    k_agg_fc<<<aggGrid, TB, 0, stream>>>(bufXL2, row_off, csr_src, dinv, b2, Wfc, bfc, out, N);
}